// Round 10
// baseline (240.891 us; speedup 1.0000x reference)
//
#include <hip/hip_runtime.h>

typedef unsigned short ushort_t;
typedef unsigned int uint_t;
typedef __bf16 bf16x8 __attribute__((ext_vector_type(8)));
typedef __bf16 bf16x4 __attribute__((ext_vector_type(4)));
typedef float f32x4 __attribute__((ext_vector_type(4)));
typedef ushort_t u16x4 __attribute__((ext_vector_type(4)));

#define NSEQ 4096
#define DIMM 768
#define NQKV 2304
#define HEADS 12
#define LOG2E 1.4426950408889634f

#if __has_builtin(__builtin_amdgcn_exp2f)
#define EXP2(x) __builtin_amdgcn_exp2f(x)
#else
#define EXP2(x) exp2f(x)
#endif

// Fragment-major packing: element (row,k) lives at
//   ((row>>4)*KB + (k>>3))*128 + (row&15)*8 + (k&7)      [KB = K/8]

__device__ __forceinline__ ushort_t f2bf(float f) {
    uint_t u = __float_as_uint(f);
    u = u + 0x7fffu + ((u >> 16) & 1u);
    return (ushort_t)(u >> 16);
}
__device__ __forceinline__ f32x4 zero4() {
    f32x4 v = {0.f, 0.f, 0.f, 0.f};
    return v;
}

// ---------------- fused prep: X cvt+pack, Wqkv pack, Wout pack (one launch)
__device__ __forceinline__ void pack_w_tile(const float* __restrict__ src,
                                            ushort_t* __restrict__ dst,
                                            int K, int N, int bk, int bn, int t,
                                            ushort_t* Ls) {
    const int tr = t >> 4, tc = t & 15;
#pragma unroll
    for (int i = 0; i < 4; ++i) {
        int r = tr + 16 * i;  // k within tile
        float4 v = *(const float4*)(&src[(size_t)(bk + r) * N + bn + tc * 4]);
        const float* vv = (const float*)&v;
#pragma unroll
        for (int j = 0; j < 4; ++j) Ls[(tc * 4 + j) * 72 + r] = f2bf(vv[j]);
    }
    __syncthreads();
    const int KB = K >> 3;
    const int n = t >> 2;
    const int ks = t & 3;
    const int gn = bn + n;
    size_t base = ((size_t)(gn >> 4) * KB + ((bk + ks * 16) >> 3)) * 128 + (gn & 15) * 8;
    *(uint4*)(&dst[base])       = *(const uint4*)(&Ls[n * 72 + ks * 16]);
    *(uint4*)(&dst[base + 128]) = *(const uint4*)(&Ls[n * 72 + ks * 16 + 8]);
}

#define CVT_BLOCKS   3072                 // TSZ/4/256
#define PW1_BLOCKS   (12 * 36)            // Wqkv 64x64 tiles
#define PW2_BLOCKS   (12 * 12)            // Wout tiles

__global__ __launch_bounds__(256) void prep_kernel(
    const float* __restrict__ X, const float* __restrict__ Wqkv, const float* __restrict__ Wout,
    ushort_t* __restrict__ Ap, ushort_t* __restrict__ Wqp, ushort_t* __restrict__ Wop)
{
    __shared__ ushort_t Ls[64 * 72];
    const int b = blockIdx.x;
    const int t = threadIdx.x;
    if (b < CVT_BLOCKS) {
        int i = b * 256 + t;
        int row = i / (DIMM / 4);
        int k0 = (i - row * (DIMM / 4)) * 4;
        float4 v = *(const float4*)(&X[(size_t)row * DIMM + k0]);
        u16x4 p = { f2bf(v.x), f2bf(v.y), f2bf(v.z), f2bf(v.w) };
        size_t idx = ((size_t)(row >> 4) * (DIMM / 8) + (k0 >> 3)) * 128 + (row & 15) * 8 + (k0 & 7);
        *(u16x4*)(&Ap[idx]) = p;
    } else if (b < CVT_BLOCKS + PW1_BLOCKS) {
        int j = b - CVT_BLOCKS;
        pack_w_tile(Wqkv, Wqp, DIMM, NQKV, (j % 12) * 64, (j / 12) * 64, t, Ls);
    } else {
        int j = b - CVT_BLOCKS - PW1_BLOCKS;
        pack_w_tile(Wout, Wop, DIMM, DIMM, (j % 12) * 64, (j / 12) * 64, t, Ls);
    }
}

// ---------------- QKV GEMM: 4x8 acc tiles (wave = 64 m x 128 n), LDS-free, frag-packed
#define QKV_LOAD8(af, bfv, kt) do {                                                           \
    _Pragma("unroll")                                                                         \
    for (int mi = 0; mi < 4; ++mi)                                                            \
        af[mi] = *(const bf16x8*)(&Ap[((size_t)(amb + mi) * KB + (kt) * 4 + g) * 128 + m16 * 8]); \
    _Pragma("unroll")                                                                         \
    for (int nj = 0; nj < 8; ++nj)                                                            \
        bfv[nj] = *(const bf16x8*)(&Bp[((size_t)(bnb + nj) * KB + (kt) * 4 + g) * 128 + m16 * 8]); \
} while (0)

__global__ __launch_bounds__(128, 2) void qkv_gemm_kernel(
    const ushort_t* __restrict__ Ap, const ushort_t* __restrict__ Bp,
    ushort_t* __restrict__ Qp, ushort_t* __restrict__ Kp, ushort_t* __restrict__ Vp)
{
    const int t = threadIdx.x;
    const int lane = t & 63;
    const int w = t >> 6;            // 0..1
    const int m16 = lane & 15;
    const int g = lane >> 4;
    const int bm = blockIdx.y * 64;
    const int bn = blockIdx.x * 256;
    const int wcol = w * 128;
    const int amb = bm >> 4;
    const int bnb = (bn + wcol) >> 4;
    const int KB = DIMM / 8;  // 96
    const int which = bn / DIMM;  // 0=Q 1=K 2=V (256-tile never crosses: 768%256==0)
    const int ghi = g >> 1, glo = g & 1;

    f32x4 acc[4][8];
#pragma unroll
    for (int i = 0; i < 4; ++i)
#pragma unroll
        for (int j = 0; j < 8; ++j) acc[i][j] = zero4();

    if (which < 2) {
        // transposed product: acc[mi][nj] rows = channel (g*4+r), cols = seq (m16)
        for (int kt = 0; kt < 24; ++kt) {
            bf16x8 af[4], bfv[8];
            QKV_LOAD8(af, bfv, kt);
#pragma unroll
            for (int mi = 0; mi < 4; ++mi)
#pragma unroll
                for (int nj = 0; nj < 8; ++nj)
                    acc[mi][nj] = __builtin_amdgcn_mfma_f32_16x16x32_bf16(bfv[nj], af[mi], acc[mi][nj], 0, 0, 0);
        }
        ushort_t* dst = (which == 0) ? Qp : Kp;
        const float scale = (which == 0) ? LOG2E : 1.0f;
        const int cb = bn - which * DIMM + wcol;  // multiple of 64
#pragma unroll
        for (int mi = 0; mi < 4; ++mi) {
            int sblk = amb + mi;
#pragma unroll
            for (int nj = 0; nj < 8; ++nj) {
                int h = (cb >> 6) + (nj >> 2);
                size_t idx = (((size_t)h * 256 + sblk) * 8 + (nj & 3) * 2 + ghi) * 128 + m16 * 8 + glo * 4;
                u16x4 pk = { f2bf(acc[mi][nj][0] * scale), f2bf(acc[mi][nj][1] * scale),
                             f2bf(acc[mi][nj][2] * scale), f2bf(acc[mi][nj][3] * scale) };
                *(u16x4*)(&dst[idx]) = pk;
            }
        }
    } else {
        // original orientation: acc[mi][nj] rows = key (g*4+r), cols = d (m16)
        for (int kt = 0; kt < 24; ++kt) {
            bf16x8 af[4], bfv[8];
            QKV_LOAD8(af, bfv, kt);
#pragma unroll
            for (int mi = 0; mi < 4; ++mi)
#pragma unroll
                for (int nj = 0; nj < 8; ++nj)
                    acc[mi][nj] = __builtin_amdgcn_mfma_f32_16x16x32_bf16(af[mi], bfv[nj], acc[mi][nj], 0, 0, 0);
        }
        const int cb = bn - 2 * DIMM + wcol;  // multiple of 64
        const int kb8 = bm >> 3;
#pragma unroll
        for (int mi = 0; mi < 4; ++mi) {
#pragma unroll
            for (int nj = 0; nj < 8; ++nj) {
                int h = (cb >> 6) + (nj >> 2);
                size_t idx = (((size_t)h * 512 + kb8 + mi * 2 + ghi) * 4 + (nj & 3)) * 128 + m16 * 8 + glo * 4;
                u16x4 pk = { f2bf(acc[mi][nj][0]), f2bf(acc[mi][nj][1]),
                             f2bf(acc[mi][nj][2]), f2bf(acc[mi][nj][3]) };
                *(u16x4*)(&Vp[idx]) = pk;
            }
        }
    }
}

// ---------------- Flash attention: q-tile 64 PER WAVE (1-wave blocks), max-free,
// barrier-free, key-split x2. 16KB loads/kt now feed 64 MFMAs (64 FLOP/B at L1).
__global__ __launch_bounds__(64, 2) void attn_kernel(
    const ushort_t* __restrict__ Qp, const ushort_t* __restrict__ Kp,
    const ushort_t* __restrict__ Vp, float* __restrict__ Opart, float* __restrict__ Lpart,
    int niter)
{
    __shared__ ushort_t Ps[64 * 72];
    const int lane = threadIdx.x & 63;
    const int m16 = lane & 15;
    const int g = lane >> 4;
    const int h = blockIdx.y;
    const int half = blockIdx.z;
    const int qb = blockIdx.x * 64;
    const int qblk0 = qb >> 4;
    const int kblk0 = half * niter * 4;
    const int vblk0 = half * niter * 8;

    bf16x8 qf[4][2];
#pragma unroll
    for (int mi = 0; mi < 4; ++mi)
#pragma unroll
        for (int kd = 0; kd < 2; ++kd)
            qf[mi][kd] = *(const bf16x8*)(&Qp[(((size_t)h * 256 + qblk0 + mi) * 8 + kd * 4 + g) * 128 + m16 * 8]);

    const ushort_t* kpA = Kp + ((size_t)h * 256 + kblk0) * 1024 + g * 128 + m16 * 8;
    const ushort_t* kpB = kpA + 2048;
    const ushort_t* vpA = Vp + ((size_t)h * 512 + vblk0) * 512 + g * 512 + m16 * 8;
    const ushort_t* vpB = vpA + 2048;

    f32x4 oacc[4][4];
#pragma unroll
    for (int mi = 0; mi < 4; ++mi)
#pragma unroll
        for (int dj = 0; dj < 4; ++dj) oacc[mi][dj] = zero4();
    f32x4 lacc[4] = {zero4(), zero4(), zero4(), zero4()};

    for (int kt = 0; kt < niter; ++kt) {
        bf16x8 kf[4][2];
        kf[0][0] = *(const bf16x8*)(kpA);
        kf[0][1] = *(const bf16x8*)(kpA + 512);
        kf[1][0] = *(const bf16x8*)(kpA + 1024);
        kf[1][1] = *(const bf16x8*)(kpA + 1536);
        kf[2][0] = *(const bf16x8*)(kpB);
        kf[2][1] = *(const bf16x8*)(kpB + 512);
        kf[3][0] = *(const bf16x8*)(kpB + 1024);
        kf[3][1] = *(const bf16x8*)(kpB + 1536);
        bf16x8 vf[4][2];
#pragma unroll
        for (int dj = 0; dj < 4; ++dj) {
            vf[dj][0] = *(const bf16x8*)(vpA + dj * 128);
            vf[dj][1] = *(const bf16x8*)(vpB + dj * 128);
        }
        kpA += 4096; kpB += 4096; vpA += 4096; vpB += 4096;

        // S^T: rows=keys (g*4+r), cols=q (m16); p = 2^s (log2e baked into Q)
#pragma unroll
        for (int nj = 0; nj < 4; ++nj) {
#pragma unroll
            for (int mi = 0; mi < 4; ++mi) {
                f32x4 st = zero4();
                st = __builtin_amdgcn_mfma_f32_16x16x32_bf16(kf[nj][0], qf[mi][0], st, 0, 0, 0);
                st = __builtin_amdgcn_mfma_f32_16x16x32_bf16(kf[nj][1], qf[mi][1], st, 0, 0, 0);
                f32x4 p;
#pragma unroll
                for (int r = 0; r < 4; ++r) p[r] = EXP2(st[r]);
                lacc[mi] += p;
                bf16x4 pk = { (__bf16)p[0], (__bf16)p[1], (__bf16)p[2], (__bf16)p[3] };
                *(bf16x4*)(&Ps[(mi * 16 + m16) * 72 + nj * 16 + g * 4]) = pk;
            }
        }
        // PV: read P A-frags per mi (wave-private LDS, in-order DS ops, no barrier)
#pragma unroll
        for (int mi = 0; mi < 4; ++mi) {
            bf16x8 pf0 = *(const bf16x8*)(&Ps[(mi * 16 + m16) * 72 + g * 8]);
            bf16x8 pf1 = *(const bf16x8*)(&Ps[(mi * 16 + m16) * 72 + 32 + g * 8]);
#pragma unroll
            for (int dj = 0; dj < 4; ++dj) {
                oacc[mi][dj] = __builtin_amdgcn_mfma_f32_16x16x32_bf16(pf0, vf[dj][0], oacc[mi][dj], 0, 0, 0);
                oacc[mi][dj] = __builtin_amdgcn_mfma_f32_16x16x32_bf16(pf1, vf[dj][1], oacc[mi][dj], 0, 0, 0);
            }
        }
    }

    float* Oph = Opart + (size_t)half * NSEQ * DIMM;
    float* Lph = Lpart + (size_t)half * HEADS * NSEQ + (size_t)h * NSEQ;
#pragma unroll
    for (int mi = 0; mi < 4; ++mi) {
        float l = (lacc[mi][0] + lacc[mi][1]) + (lacc[mi][2] + lacc[mi][3]);
        l += __shfl_xor(l, 16);
        l += __shfl_xor(l, 32);
        if (g == 0) Lph[qb + mi * 16 + m16] = l;
    }
#pragma unroll
    for (int mi = 0; mi < 4; ++mi) {
#pragma unroll
        for (int r = 0; r < 4; ++r) {
            int row = qb + mi * 16 + g * 4 + r;
#pragma unroll
            for (int dj = 0; dj < 4; ++dj)
                Oph[(size_t)row * DIMM + h * 64 + dj * 16 + m16] = oacc[mi][dj][r];
        }
    }
}

// ---------------- Merge nsplit partials -> Xap frag-major bf16
__global__ __launch_bounds__(256) void merge_kernel(
    const float* __restrict__ Opart, const float* __restrict__ Lpart,
    ushort_t* __restrict__ Xap, int nsplit)
{
    int i = blockIdx.x * 256 + threadIdx.x;
    int row = i / (DIMM / 4);
    int col0 = (i - row * (DIMM / 4)) * 4;
    int h = col0 >> 6;
    float l = 0.f;
    f32x4 o = zero4();
    for (int s = 0; s < nsplit; ++s) {
        l += Lpart[(size_t)s * HEADS * NSEQ + (size_t)h * NSEQ + row];
        f32x4 ov = *(const f32x4*)(&Opart[(size_t)s * NSEQ * DIMM + (size_t)row * DIMM + col0]);
        o += ov;
    }
    float inv = 1.0f / l;
    u16x4 p = { f2bf(o[0] * inv), f2bf(o[1] * inv), f2bf(o[2] * inv), f2bf(o[3] * inv) };
    size_t idx = ((size_t)(row >> 4) * (DIMM / 8) + (col0 >> 3)) * 128 + (row & 15) * 8 + (col0 & 7);
    *(u16x4*)(&Xap[idx]) = p;
}

// ---------------- Output projection: 4x8 acc tiles (wave = 64 m x 128 n)
__global__ __launch_bounds__(128, 2) void out_gemm_kernel(
    const ushort_t* __restrict__ Ap, const ushort_t* __restrict__ Bp,
    const float* __restrict__ bias, float* __restrict__ out)
{
    const int t = threadIdx.x;
    const int lane = t & 63;
    const int w = t >> 6;
    const int m16 = lane & 15;
    const int g = lane >> 4;
    const int bm = blockIdx.y * 128;
    const int bn = blockIdx.x * 128;
    const int amb = (bm + w * 64) >> 4;
    const int bnb = bn >> 4;
    const int KB = DIMM / 8;  // 96

    f32x4 acc[4][8];
#pragma unroll
    for (int i = 0; i < 4; ++i)
#pragma unroll
        for (int j = 0; j < 8; ++j) acc[i][j] = zero4();

    for (int kt = 0; kt < 24; ++kt) {
        bf16x8 af[4], bfv[8];
        QKV_LOAD8(af, bfv, kt);
#pragma unroll
        for (int mi = 0; mi < 4; ++mi)
#pragma unroll
            for (int nj = 0; nj < 8; ++nj)
                acc[mi][nj] = __builtin_amdgcn_mfma_f32_16x16x32_bf16(af[mi], bfv[nj], acc[mi][nj], 0, 0, 0);
    }
#pragma unroll
    for (int mi = 0; mi < 4; ++mi) {
#pragma unroll
        for (int nj = 0; nj < 8; ++nj) {
            int col = bn + nj * 16 + m16;
            float bv = bias[col];
#pragma unroll
            for (int r = 0; r < 4; ++r) {
                int row = bm + w * 64 + mi * 16 + g * 4 + r;
                out[(size_t)row * DIMM + col] = acc[mi][nj][r] + bv;
            }
        }
    }
}

extern "C" void kernel_launch(void* const* d_in, const int* in_sizes, int n_in,
                              void* d_out, int out_size, void* d_ws, size_t ws_size,
                              hipStream_t stream) {
    (void)in_sizes; (void)n_in; (void)out_size; (void)ws_size;
    const float* X    = (const float*)d_in[0];
    const float* Wqkv = (const float*)d_in[1];
    const float* Wout = (const float*)d_in[2];
    const float* bout = (const float*)d_in[3];
    float* out = (float*)d_out;

    const size_t TSZ = (size_t)NSEQ * DIMM;  // 3145728
    const int nsplit = 2;

    unsigned char* p = (unsigned char*)d_ws;
    ushort_t* Ap  = (ushort_t*)p; p += TSZ * 2;
    ushort_t* Wqp = (ushort_t*)p; p += (size_t)NQKV * DIMM * 2;
    ushort_t* Wop = (ushort_t*)p; p += (size_t)DIMM * DIMM * 2;
    ushort_t* Qp  = (ushort_t*)p; p += TSZ * 2;
    ushort_t* Kp  = (ushort_t*)p; p += TSZ * 2;
    ushort_t* Vp  = (ushort_t*)p; p += TSZ * 2;
    ushort_t* Xap = (ushort_t*)p; p += TSZ * 2;
    float* Opart  = (float*)p;    p += (size_t)nsplit * TSZ * 4;
    float* Lpart  = (float*)p;

    const int niter = (NSEQ / 64) / nsplit;  // 32

    prep_kernel<<<CVT_BLOCKS + PW1_BLOCKS + PW2_BLOCKS, 256, 0, stream>>>(X, Wqkv, Wout, Ap, Wqp, Wop);
    qkv_gemm_kernel<<<dim3(NQKV / 256, NSEQ / 64), 128, 0, stream>>>(Ap, Wqp, Qp, Kp, Vp);
    attn_kernel<<<dim3(NSEQ / 64, HEADS, nsplit), 64, 0, stream>>>(Qp, Kp, Vp, Opart, Lpart, niter);
    merge_kernel<<<TSZ / 4 / 256, 256, 0, stream>>>(Opart, Lpart, Xap, nsplit);
    out_gemm_kernel<<<dim3(DIMM / 128, NSEQ / 128), 128, 0, stream>>>(Xap, Wop, bout, out);
}

// Round 11
// 204.327 us; speedup vs baseline: 1.1789x; 1.1789x over previous
//
#include <hip/hip_runtime.h>

typedef unsigned short ushort_t;
typedef unsigned int uint_t;
typedef __bf16 bf16x8 __attribute__((ext_vector_type(8)));
typedef __bf16 bf16x4 __attribute__((ext_vector_type(4)));
typedef float f32x4 __attribute__((ext_vector_type(4)));
typedef ushort_t u16x4 __attribute__((ext_vector_type(4)));

#define NSEQ 4096
#define DIMM 768
#define NQKV 2304
#define HEADS 12
#define LOG2E 1.4426950408889634f

#if __has_builtin(__builtin_amdgcn_exp2f)
#define EXP2(x) __builtin_amdgcn_exp2f(x)
#else
#define EXP2(x) exp2f(x)
#endif

// Fragment-major packing: element (row,k) lives at
//   ((row>>4)*KB + (k>>3))*128 + (row&15)*8 + (k&7)      [KB = K/8]

__device__ __forceinline__ ushort_t f2bf(float f) {
    uint_t u = __float_as_uint(f);
    u = u + 0x7fffu + ((u >> 16) & 1u);
    return (ushort_t)(u >> 16);
}
__device__ __forceinline__ f32x4 zero4() {
    f32x4 v = {0.f, 0.f, 0.f, 0.f};
    return v;
}

// ---------------- fused prep: X cvt+pack, Wqkv pack, Wout pack (one launch)
__device__ __forceinline__ void pack_w_tile(const float* __restrict__ src,
                                            ushort_t* __restrict__ dst,
                                            int K, int N, int bk, int bn, int t,
                                            ushort_t* Ls) {
    const int tr = t >> 4, tc = t & 15;
#pragma unroll
    for (int i = 0; i < 4; ++i) {
        int r = tr + 16 * i;  // k within tile
        float4 v = *(const float4*)(&src[(size_t)(bk + r) * N + bn + tc * 4]);
        const float* vv = (const float*)&v;
#pragma unroll
        for (int j = 0; j < 4; ++j) Ls[(tc * 4 + j) * 72 + r] = f2bf(vv[j]);
    }
    __syncthreads();
    const int KB = K >> 3;
    const int n = t >> 2;
    const int ks = t & 3;
    const int gn = bn + n;
    size_t base = ((size_t)(gn >> 4) * KB + ((bk + ks * 16) >> 3)) * 128 + (gn & 15) * 8;
    *(uint4*)(&dst[base])       = *(const uint4*)(&Ls[n * 72 + ks * 16]);
    *(uint4*)(&dst[base + 128]) = *(const uint4*)(&Ls[n * 72 + ks * 16 + 8]);
}

#define CVT_BLOCKS   3072                 // TSZ/4/256
#define PW1_BLOCKS   (12 * 36)            // Wqkv 64x64 tiles
#define PW2_BLOCKS   (12 * 12)            // Wout tiles

__global__ __launch_bounds__(256) void prep_kernel(
    const float* __restrict__ X, const float* __restrict__ Wqkv, const float* __restrict__ Wout,
    ushort_t* __restrict__ Ap, ushort_t* __restrict__ Wqp, ushort_t* __restrict__ Wop)
{
    __shared__ ushort_t Ls[64 * 72];
    const int b = blockIdx.x;
    const int t = threadIdx.x;
    if (b < CVT_BLOCKS) {
        int i = b * 256 + t;
        int row = i / (DIMM / 4);
        int k0 = (i - row * (DIMM / 4)) * 4;
        float4 v = *(const float4*)(&X[(size_t)row * DIMM + k0]);
        u16x4 p = { f2bf(v.x), f2bf(v.y), f2bf(v.z), f2bf(v.w) };
        size_t idx = ((size_t)(row >> 4) * (DIMM / 8) + (k0 >> 3)) * 128 + (row & 15) * 8 + (k0 & 7);
        *(u16x4*)(&Ap[idx]) = p;
    } else if (b < CVT_BLOCKS + PW1_BLOCKS) {
        int j = b - CVT_BLOCKS;
        pack_w_tile(Wqkv, Wqp, DIMM, NQKV, (j % 12) * 64, (j / 12) * 64, t, Ls);
    } else {
        int j = b - CVT_BLOCKS - PW1_BLOCKS;
        pack_w_tile(Wout, Wop, DIMM, DIMM, (j % 12) * 64, (j / 12) * 64, t, Ls);
    }
}

// ---------------- QKV GEMM (LDS-free, frag-packed, reg double-buffered) — r8/r9 proven version
#define QKV_LOAD(af, bfv, kt) do {                                                            \
    _Pragma("unroll")                                                                         \
    for (int mi = 0; mi < 4; ++mi)                                                            \
        af[mi] = *(const bf16x8*)(&Ap[((size_t)(amb + mi) * KB + (kt) * 4 + g) * 128 + m16 * 8]); \
    _Pragma("unroll")                                                                         \
    for (int nj = 0; nj < 4; ++nj)                                                            \
        bfv[nj] = *(const bf16x8*)(&Bp[((size_t)(bnb + nj) * KB + (kt) * 4 + g) * 128 + m16 * 8]); \
} while (0)

__global__ __launch_bounds__(256) void qkv_gemm_kernel(
    const ushort_t* __restrict__ Ap, const ushort_t* __restrict__ Bp,
    ushort_t* __restrict__ Qp, ushort_t* __restrict__ Kp, ushort_t* __restrict__ Vp)
{
    const int t = threadIdx.x;
    const int lane = t & 63;
    const int w = t >> 6;
    const int m16 = lane & 15;
    const int g = lane >> 4;
    const int wrow = (w >> 1) * 64;
    const int wcol = (w & 1) * 64;
    const int bm = blockIdx.y * 128;
    const int bn = blockIdx.x * 128;
    const int amb = (bm + wrow) >> 4;
    const int bnb = (bn + wcol) >> 4;
    const int KB = DIMM / 8;  // 96
    const int which = bn / DIMM;  // 0=Q 1=K 2=V

    f32x4 acc[4][4];
#pragma unroll
    for (int i = 0; i < 4; ++i)
#pragma unroll
        for (int j = 0; j < 4; ++j) acc[i][j] = zero4();

    bf16x8 af0[4], bf0[4], af1[4], bf1[4];
    QKV_LOAD(af0, bf0, 0);

    if (which < 2) {
        // transposed product: acc rows = out-channel, cols = seq
        for (int kt = 0; kt < 24; kt += 2) {
            QKV_LOAD(af1, bf1, kt + 1);
#pragma unroll
            for (int mi = 0; mi < 4; ++mi)
#pragma unroll
                for (int nj = 0; nj < 4; ++nj)
                    acc[mi][nj] = __builtin_amdgcn_mfma_f32_16x16x32_bf16(bf0[nj], af0[mi], acc[mi][nj], 0, 0, 0);
            if (kt + 2 < 24) QKV_LOAD(af0, bf0, kt + 2);
#pragma unroll
            for (int mi = 0; mi < 4; ++mi)
#pragma unroll
                for (int nj = 0; nj < 4; ++nj)
                    acc[mi][nj] = __builtin_amdgcn_mfma_f32_16x16x32_bf16(bf1[nj], af1[mi], acc[mi][nj], 0, 0, 0);
        }
        ushort_t* dst = (which == 0) ? Qp : Kp;
        const float scale = (which == 0) ? LOG2E : 1.0f;
        const int cb = bn - which * DIMM + wcol;
        const int h = cb >> 6;
        const int ghi = g >> 1, glo = g & 1;
#pragma unroll
        for (int mi = 0; mi < 4; ++mi) {
            int sblk = amb + mi;
#pragma unroll
            for (int nj = 0; nj < 4; ++nj) {
                size_t idx = (((size_t)h * 256 + sblk) * 8 + nj * 2 + ghi) * 128 + m16 * 8 + glo * 4;
                u16x4 pk = { f2bf(acc[mi][nj][0] * scale), f2bf(acc[mi][nj][1] * scale),
                             f2bf(acc[mi][nj][2] * scale), f2bf(acc[mi][nj][3] * scale) };
                *(u16x4*)(&dst[idx]) = pk;
            }
        }
    } else {
        // original orientation: acc rows = key, cols = d
        for (int kt = 0; kt < 24; kt += 2) {
            QKV_LOAD(af1, bf1, kt + 1);
#pragma unroll
            for (int mi = 0; mi < 4; ++mi)
#pragma unroll
                for (int nj = 0; nj < 4; ++nj)
                    acc[mi][nj] = __builtin_amdgcn_mfma_f32_16x16x32_bf16(af0[mi], bf0[nj], acc[mi][nj], 0, 0, 0);
            if (kt + 2 < 24) QKV_LOAD(af0, bf0, kt + 2);
#pragma unroll
            for (int mi = 0; mi < 4; ++mi)
#pragma unroll
                for (int nj = 0; nj < 4; ++nj)
                    acc[mi][nj] = __builtin_amdgcn_mfma_f32_16x16x32_bf16(af1[mi], bf1[nj], acc[mi][nj], 0, 0, 0);
        }
        const int cb = bn - 2 * DIMM + wcol;
        const int h = cb >> 6;
        const int ghi = g >> 1, glo = g & 1;
        const int kb8 = (bm + wrow) >> 3;
#pragma unroll
        for (int mi = 0; mi < 4; ++mi) {
#pragma unroll
            for (int nj = 0; nj < 4; ++nj) {
                size_t idx = (((size_t)h * 512 + kb8 + mi * 2 + ghi) * 4 + nj) * 128 + m16 * 8 + glo * 4;
                u16x4 pk = { f2bf(acc[mi][nj][0]), f2bf(acc[mi][nj][1]),
                             f2bf(acc[mi][nj][2]), f2bf(acc[mi][nj][3]) };
                *(u16x4*)(&Vp[idx]) = pk;
            }
        }
    }
}

// ---------------- Flash attention: r8 proven config (q=32/wave, 4-wave blocks, single-buffer)
// with raised occupancy cap: launch_bounds(256,4) -> 4 blocks/CU (VGPR 64, LDS 18KB allow it)
__global__ __launch_bounds__(256, 4) void attn_kernel(
    const ushort_t* __restrict__ Qp, const ushort_t* __restrict__ Kp,
    const ushort_t* __restrict__ Vp, float* __restrict__ Opart, float* __restrict__ Lpart,
    int niter)
{
    __shared__ ushort_t Ps[4][32 * 72];
    const int t = threadIdx.x;
    const int lane = t & 63;
    const int w = t >> 6;
    const int m16 = lane & 15;
    const int g = lane >> 4;
    const int h = blockIdx.y;
    const int half = blockIdx.z;
    const int qb = blockIdx.x * 128 + w * 32;
    const int qblk0 = qb >> 4;
    const int kblk0 = half * niter * 4;
    const int vblk0 = half * niter * 8;

    bf16x8 qf[2][2];
#pragma unroll
    for (int mi = 0; mi < 2; ++mi)
#pragma unroll
        for (int kd = 0; kd < 2; ++kd)
            qf[mi][kd] = *(const bf16x8*)(&Qp[(((size_t)h * 256 + qblk0 + mi) * 8 + kd * 4 + g) * 128 + m16 * 8]);

    const ushort_t* kpA = Kp + ((size_t)h * 256 + kblk0) * 1024 + g * 128 + m16 * 8;
    const ushort_t* kpB = kpA + 2048;
    const ushort_t* vpA = Vp + ((size_t)h * 512 + vblk0) * 512 + g * 512 + m16 * 8;
    const ushort_t* vpB = vpA + 2048;

    f32x4 oacc[2][4];
#pragma unroll
    for (int mi = 0; mi < 2; ++mi)
#pragma unroll
        for (int dj = 0; dj < 4; ++dj) oacc[mi][dj] = zero4();
    f32x4 lacc[2] = {zero4(), zero4()};

#pragma unroll 4
    for (int kt = 0; kt < niter; ++kt) {
        bf16x8 kf[4][2];
        kf[0][0] = *(const bf16x8*)(kpA);
        kf[0][1] = *(const bf16x8*)(kpA + 512);
        kf[1][0] = *(const bf16x8*)(kpA + 1024);
        kf[1][1] = *(const bf16x8*)(kpA + 1536);
        kf[2][0] = *(const bf16x8*)(kpB);
        kf[2][1] = *(const bf16x8*)(kpB + 512);
        kf[3][0] = *(const bf16x8*)(kpB + 1024);
        kf[3][1] = *(const bf16x8*)(kpB + 1536);
        bf16x8 vf[4][2];
#pragma unroll
        for (int dj = 0; dj < 4; ++dj) {
            vf[dj][0] = *(const bf16x8*)(vpA + dj * 128);
            vf[dj][1] = *(const bf16x8*)(vpB + dj * 128);
        }
        kpA += 4096; kpB += 4096; vpA += 4096; vpB += 4096;

        // S^T: rows=keys (g*4+r), cols=q (m16); p = 2^s (log2e baked into Q)
#pragma unroll
        for (int nj = 0; nj < 4; ++nj) {
#pragma unroll
            for (int mi = 0; mi < 2; ++mi) {
                f32x4 st = zero4();
#pragma unroll
                for (int kd = 0; kd < 2; ++kd)
                    st = __builtin_amdgcn_mfma_f32_16x16x32_bf16(kf[nj][kd], qf[mi][kd], st, 0, 0, 0);
                f32x4 p;
#pragma unroll
                for (int r = 0; r < 4; ++r) p[r] = EXP2(st[r]);
                lacc[mi] += p;
                bf16x4 pk = { (__bf16)p[0], (__bf16)p[1], (__bf16)p[2], (__bf16)p[3] };
                *(bf16x4*)(&Ps[w][(mi * 16 + m16) * 72 + nj * 16 + g * 4]) = pk;
            }
        }
        // P A-frags (wave-private LDS; in-order DS ops, no barrier)
        bf16x8 pf[2][2];
#pragma unroll
        for (int mi = 0; mi < 2; ++mi)
#pragma unroll
            for (int kc = 0; kc < 2; ++kc)
                pf[mi][kc] = *(const bf16x8*)(&Ps[w][(mi * 16 + m16) * 72 + kc * 32 + g * 8]);
#pragma unroll
        for (int mi = 0; mi < 2; ++mi)
#pragma unroll
            for (int dj = 0; dj < 4; ++dj)
#pragma unroll
                for (int kc = 0; kc < 2; ++kc)
                    oacc[mi][dj] = __builtin_amdgcn_mfma_f32_16x16x32_bf16(pf[mi][kc], vf[dj][kc], oacc[mi][dj], 0, 0, 0);
    }

    float* Oph = Opart + (size_t)half * NSEQ * DIMM;
    float* Lph = Lpart + (size_t)half * HEADS * NSEQ + (size_t)h * NSEQ;
#pragma unroll
    for (int mi = 0; mi < 2; ++mi) {
        float l = (lacc[mi][0] + lacc[mi][1]) + (lacc[mi][2] + lacc[mi][3]);
        l += __shfl_xor(l, 16);
        l += __shfl_xor(l, 32);
        if (g == 0) Lph[qb + mi * 16 + m16] = l;
    }
#pragma unroll
    for (int mi = 0; mi < 2; ++mi) {
#pragma unroll
        for (int r = 0; r < 4; ++r) {
            int row = qb + mi * 16 + g * 4 + r;
#pragma unroll
            for (int dj = 0; dj < 4; ++dj)
                Oph[(size_t)row * DIMM + h * 64 + dj * 16 + m16] = oacc[mi][dj][r];
        }
    }
}

// ---------------- Merge nsplit partials -> Xap frag-major bf16
__global__ __launch_bounds__(256) void merge_kernel(
    const float* __restrict__ Opart, const float* __restrict__ Lpart,
    ushort_t* __restrict__ Xap, int nsplit)
{
    int i = blockIdx.x * 256 + threadIdx.x;
    int row = i / (DIMM / 4);
    int col0 = (i - row * (DIMM / 4)) * 4;
    int h = col0 >> 6;
    float l = 0.f;
    f32x4 o = zero4();
    for (int s = 0; s < nsplit; ++s) {
        l += Lpart[(size_t)s * HEADS * NSEQ + (size_t)h * NSEQ + row];
        f32x4 ov = *(const f32x4*)(&Opart[(size_t)s * NSEQ * DIMM + (size_t)row * DIMM + col0]);
        o += ov;
    }
    float inv = 1.0f / l;
    u16x4 p = { f2bf(o[0] * inv), f2bf(o[1] * inv), f2bf(o[2] * inv), f2bf(o[3] * inv) };
    size_t idx = ((size_t)(row >> 4) * (DIMM / 8) + (col0 >> 3)) * 128 + (row & 15) * 8 + (col0 & 7);
    *(u16x4*)(&Xap[idx]) = p;
}

// ---------------- Output projection: 32x64 wave tiles, 1-wave blocks (6 waves/CU)
__global__ __launch_bounds__(64, 4) void out_gemm_kernel(
    const ushort_t* __restrict__ Ap, const ushort_t* __restrict__ Bp,
    const float* __restrict__ bias, float* __restrict__ out)
{
    const int lane = threadIdx.x & 63;
    const int m16 = lane & 15;
    const int g = lane >> 4;
    const int bm = blockIdx.y * 32;
    const int bn = blockIdx.x * 64;
    const int amb = bm >> 4;
    const int bnb = bn >> 4;
    const int KB = DIMM / 8;  // 96

    f32x4 acc[2][4];
#pragma unroll
    for (int i = 0; i < 2; ++i)
#pragma unroll
        for (int j = 0; j < 4; ++j) acc[i][j] = zero4();

#pragma unroll 2
    for (int kt = 0; kt < 24; ++kt) {
        bf16x8 af[2], bfv[4];
#pragma unroll
        for (int mi = 0; mi < 2; ++mi)
            af[mi] = *(const bf16x8*)(&Ap[((size_t)(amb + mi) * KB + kt * 4 + g) * 128 + m16 * 8]);
#pragma unroll
        for (int nj = 0; nj < 4; ++nj)
            bfv[nj] = *(const bf16x8*)(&Bp[((size_t)(bnb + nj) * KB + kt * 4 + g) * 128 + m16 * 8]);
#pragma unroll
        for (int mi = 0; mi < 2; ++mi)
#pragma unroll
            for (int nj = 0; nj < 4; ++nj)
                acc[mi][nj] = __builtin_amdgcn_mfma_f32_16x16x32_bf16(af[mi], bfv[nj], acc[mi][nj], 0, 0, 0);
    }
#pragma unroll
    for (int mi = 0; mi < 2; ++mi) {
#pragma unroll
        for (int nj = 0; nj < 4; ++nj) {
            int col = bn + nj * 16 + m16;
            float bv = bias[col];
#pragma unroll
            for (int r = 0; r < 4; ++r) {
                int row = bm + mi * 16 + g * 4 + r;
                out[(size_t)row * DIMM + col] = acc[mi][nj][r] + bv;
            }
        }
    }
}

extern "C" void kernel_launch(void* const* d_in, const int* in_sizes, int n_in,
                              void* d_out, int out_size, void* d_ws, size_t ws_size,
                              hipStream_t stream) {
    (void)in_sizes; (void)n_in; (void)out_size;
    const float* X    = (const float*)d_in[0];
    const float* Wqkv = (const float*)d_in[1];
    const float* Wout = (const float*)d_in[2];
    const float* bout = (const float*)d_in[3];
    float* out = (float*)d_out;

    const size_t TSZ = (size_t)NSEQ * DIMM;  // 3145728
    const size_t fixed = TSZ * 2 * 5 + (size_t)NQKV * DIMM * 2 + (size_t)DIMM * DIMM * 2;
    const size_t per_split = TSZ * 4 + (size_t)HEADS * NSEQ * 4;
    const int nsplit = (ws_size >= fixed + 4 * per_split) ? 4 : 2;

    unsigned char* p = (unsigned char*)d_ws;
    ushort_t* Ap  = (ushort_t*)p; p += TSZ * 2;
    ushort_t* Wqp = (ushort_t*)p; p += (size_t)NQKV * DIMM * 2;
    ushort_t* Wop = (ushort_t*)p; p += (size_t)DIMM * DIMM * 2;
    ushort_t* Qp  = (ushort_t*)p; p += TSZ * 2;
    ushort_t* Kp  = (ushort_t*)p; p += TSZ * 2;
    ushort_t* Vp  = (ushort_t*)p; p += TSZ * 2;
    ushort_t* Xap = (ushort_t*)p; p += TSZ * 2;
    float* Opart  = (float*)p;    p += (size_t)nsplit * TSZ * 4;
    float* Lpart  = (float*)p;

    const int niter = (NSEQ / 64) / nsplit;

    prep_kernel<<<CVT_BLOCKS + PW1_BLOCKS + PW2_BLOCKS, 256, 0, stream>>>(X, Wqkv, Wout, Ap, Wqp, Wop);
    qkv_gemm_kernel<<<dim3(NQKV / 128, NSEQ / 128), 256, 0, stream>>>(Ap, Wqp, Qp, Kp, Vp);
    attn_kernel<<<dim3(NSEQ / 128, HEADS, nsplit), 256, 0, stream>>>(Qp, Kp, Vp, Opart, Lpart, niter);
    merge_kernel<<<TSZ / 4 / 256, 256, 0, stream>>>(Opart, Lpart, Xap, nsplit);
    out_gemm_kernel<<<dim3(DIMM / 64, NSEQ / 32), 64, 0, stream>>>(Xap, Wop, bout, out);
}